// Round 5
// baseline (666.312 us; speedup 1.0000x reference)
//
#include <hip/hip_runtime.h>
#include <hip/hip_fp16.h>
#include <math.h>

#define N_NODES 50000
#define N_EDGES 640000
#define NGRAPH  256
#define SCHUNK  1024
#define NCHUNK  49   // ceil(50000/1024)

typedef _Float16 half8_t __attribute__((ext_vector_type(8)));
typedef _Float16 half4_t __attribute__((ext_vector_type(4)));
typedef float floatx4 __attribute__((ext_vector_type(4)));

// ------------------------------------------------------------------
// Weight prep: convert all 7 [128,128] fp32 k-major weights into the
// fp16 transposed+swizzled layout the GEMM stages into LDS:
//   wt[m][n*128 + ((k>>3)^(n&15))*8 + (k&7)]
// ------------------------------------------------------------------
__global__ void k_wprep(const float* __restrict__ lin_w,
                        const float* __restrict__ conv_W,
                        _Float16* __restrict__ wt_g)
{
    int idx = blockIdx.x * 256 + threadIdx.x;
    if (idx >= 7 * 16384) return;
    int m = idx >> 14;
    int r = idx & 16383;
    int k = r >> 7;
    int n = r & 127;
    const float* W = (m == 0) ? lin_w : conv_W + (size_t)(m - 1) * 16384;
    float v = W[(size_t)k * 128 + n];
    int slot = (k >> 3) ^ (n & 15);
    wt_g[(size_t)m * 16384 + n * 128 + slot * 8 + (k & 7)] = (_Float16)v;
}

// ------------------------------------------------------------------
// MFMA GEMM: C16[M,128] = half(A16[M,128] @ W (+bias)).
// W comes pre-swizzled fp16 (wt); staging is a straight vector copy.
// Block 256 = 4 waves; wave computes 16 rows x 128 cols via 8 N-tiles.
// Optional fused attention projections a_s/a_d (fp32).
// ------------------------------------------------------------------
__global__ __launch_bounds__(256) void k_gemm16(
    const __half* __restrict__ A, const _Float16* __restrict__ wt,
    const float* __restrict__ bias, __half* __restrict__ C16, int M,
    const float* __restrict__ asrc, const float* __restrict__ adst,
    float* __restrict__ a_s, float* __restrict__ a_d)
{
    __shared__ _Float16 Wt[128 * 128];   // 32 KB
    int tid = threadIdx.x;
    {
        const float4* wsrc = (const float4*)wt;
        float4* wl = (float4*)Wt;
        #pragma unroll
        for (int r = 0; r < 8; ++r) wl[r * 256 + tid] = wsrc[r * 256 + tid];
    }
    __syncthreads();

    int lane = tid & 63;
    int wv = tid >> 6;
    int r0 = blockIdx.x * 64 + wv * 16;
    int cl = lane & 15;
    int ks = lane >> 4;             // k-chunk group 0..3

    int arow = r0 + cl; if (arow >= M) arow = M - 1;
    const _Float16* Arow = (const _Float16*)A + (size_t)arow * 128 + ks * 8;
    half8_t afrag[4];
    #pragma unroll
    for (int kk = 0; kk < 4; ++kk)
        afrag[kk] = *(const half8_t*)(Arow + kk * 32);

    floatx4 acc[8];
    #pragma unroll
    for (int nt = 0; nt < 8; ++nt) acc[nt] = (floatx4){0.f, 0.f, 0.f, 0.f};

    #pragma unroll
    for (int kk = 0; kk < 4; ++kk) {
        #pragma unroll
        for (int nt = 0; nt < 8; ++nt) {
            int n = nt * 16 + cl;
            int slot = (kk * 4 + ks) ^ cl;
            half8_t bfrag = *(const half8_t*)&Wt[n * 128 + slot * 8];
            acc[nt] = __builtin_amdgcn_mfma_f32_16x16x32_f16(afrag[kk], bfrag, acc[nt], 0, 0, 0);
        }
    }

    int rg = lane >> 4;   // row group for C/D
    #pragma unroll
    for (int nt = 0; nt < 8; ++nt) {
        float bv = bias ? bias[nt * 16 + cl] : 0.f;
        #pragma unroll
        for (int j = 0; j < 4; ++j) {
            int row = r0 + rg * 4 + j;
            if (row < M)
                C16[(size_t)row * 128 + nt * 16 + cl] = __float2half(acc[nt][j] + bv);
        }
    }

    if (a_s) {
        float s[4][4], d[4][4];
        #pragma unroll
        for (int h = 0; h < 4; ++h)
            #pragma unroll
            for (int j = 0; j < 4; ++j) { s[h][j] = 0.f; d[h][j] = 0.f; }
        #pragma unroll
        for (int nt = 0; nt < 8; ++nt) {
            int h = nt >> 1;
            float as = asrc[h * 32 + (nt & 1) * 16 + cl];
            float ad = adst[h * 32 + (nt & 1) * 16 + cl];
            #pragma unroll
            for (int j = 0; j < 4; ++j) {
                s[h][j] += acc[nt][j] * as;
                d[h][j] += acc[nt][j] * ad;
            }
        }
        #pragma unroll
        for (int h = 0; h < 4; ++h)
            #pragma unroll
            for (int j = 0; j < 4; ++j)
                #pragma unroll
                for (int k = 1; k < 16; k <<= 1) {
                    s[h][j] += __shfl_xor(s[h][j], k);
                    d[h][j] += __shfl_xor(d[h][j], k);
                }
        if (cl == 0) {
            #pragma unroll
            for (int j = 0; j < 4; ++j) {
                int row = r0 + rg * 4 + j;
                if (row < M) {
                    #pragma unroll
                    for (int h = 0; h < 4; ++h) {
                        a_s[row * 4 + h] = s[h][j];
                        a_d[row * 4 + h] = d[h][j];
                    }
                }
            }
        }
    }
}

// ------------------------------------------------------------------
__global__ void k_cast16(const float* __restrict__ in, __half* __restrict__ out, int n4) {
    int i = blockIdx.x * blockDim.x + threadIdx.x;
    if (i < n4) {
        float4 v = ((const float4*)in)[i];
        __half2 a = __floats2half2_rn(v.x, v.y);
        __half2 b = __floats2half2_rn(v.z, v.w);
        ((__half2*)out)[i * 2] = a;
        ((__half2*)out)[i * 2 + 1] = b;
    }
}

__global__ void k_zero_i(int* p, int n) {
    int i = blockIdx.x * blockDim.x + threadIdx.x;
    if (i < n) p[i] = 0;
}

__global__ void k_zero_f(float* p, int n) {
    int i = blockIdx.x * blockDim.x + threadIdx.x;
    if (i < n) p[i] = 0.f;
}

// ------------------------------------------------------------------
// CSR build; k_fill writes packed (src, ea) int2 directly in CSR order.
// ------------------------------------------------------------------
__global__ void k_deg(const int* __restrict__ dst, int* deg) {
    int e = blockIdx.x * blockDim.x + threadIdx.x;
    if (e < N_EDGES) atomicAdd(&deg[dst[e]], 1);
}

__global__ __launch_bounds__(256) void k_chunksum(const int* __restrict__ deg, int* cs) {
    __shared__ int r[256];
    int b = blockIdx.x;
    int acc = 0;
    for (int i = threadIdx.x; i < SCHUNK; i += 256) {
        int idx = b * SCHUNK + i;
        if (idx < N_NODES) acc += deg[idx];
    }
    r[threadIdx.x] = acc; __syncthreads();
    for (int s = 128; s > 0; s >>= 1) {
        if (threadIdx.x < s) r[threadIdx.x] += r[threadIdx.x + s];
        __syncthreads();
    }
    if (threadIdx.x == 0) cs[b] = r[0];
}

__global__ void k_scanbase(const int* cs, int* base, int* offs) {
    if (threadIdx.x == 0) {
        int run = 0;
        for (int b = 0; b < NCHUNK; ++b) { base[b] = run; run += cs[b]; }
        offs[N_NODES] = run;
    }
}

__global__ __launch_bounds__(1024) void k_scanlocal(
    const int* __restrict__ deg, const int* __restrict__ base,
    int* offs, int* cursor)
{
    __shared__ int s[1024];
    int b = blockIdx.x, t = threadIdx.x;
    int idx = b * SCHUNK + t;
    int d = (idx < N_NODES) ? deg[idx] : 0;
    s[t] = d; __syncthreads();
    for (int off = 1; off < 1024; off <<= 1) {
        int v = (t >= off) ? s[t - off] : 0;
        __syncthreads();
        s[t] += v; __syncthreads();
    }
    if (idx < N_NODES) {
        int ex = s[t] - d + base[b];
        offs[idx] = ex; cursor[idx] = ex;
    }
}

__global__ void k_fill(const int* __restrict__ src, const int* __restrict__ dst,
                       const float* __restrict__ ea, int* cursor,
                       int2* __restrict__ edata)
{
    int e = blockIdx.x * blockDim.x + threadIdx.x;
    if (e < N_EDGES) {
        int p = atomicAdd(&cursor[dst[e]], 1);
        edata[p] = make_int2(src[e], __float_as_int(ea[e]));
    }
}

// ------------------------------------------------------------------
// Fused attention: softmax (2-pass, recompute logits) + weighted wx
// gather, one wave per destination node. Lanes 0-31 = even edges,
// 32-63 = odd edges; each lane covers 4 cols; head ht = cg>>3.
// ------------------------------------------------------------------
__global__ __launch_bounds__(256) void k_attn(
    const __half* __restrict__ wx16, const int2* __restrict__ edata,
    const float* __restrict__ a_s, const float* __restrict__ a_d,
    const int* __restrict__ offs, const __half* __restrict__ resid,
    __half* __restrict__ out)
{
    int lane = threadIdx.x & 63;
    int n = blockIdx.x * 4 + (threadIdx.x >> 6);
    int half_ = lane >> 5;
    int cg = lane & 31;
    int c0 = cg * 4;
    int ht = cg >> 3;
    int off0 = offs[n], off1 = offs[n + 1];
    int cnt = off1 - off0;
    float adn = a_d[n * 4 + ht];
    const _Float16* wx = (const _Float16*)wx16;

    // pass 1: per-head max over incident edges
    float mx = -3e38f;
    for (int j = half_; j < cnt; j += 2) {
        int2 ed = edata[off0 + j];
        float aev = __int_as_float(ed.y);
        float v = a_s[ed.x * 4 + ht] + adn;
        v = (v > 0.f ? v : 0.2f * v) * aev;
        mx = fmaxf(mx, v);
    }
    mx = fmaxf(mx, __shfl_xor(mx, 32));

    // pass 2: exp + weighted gather + denom
    float den = 0.f, A0 = 0.f, A1 = 0.f, A2 = 0.f, A3 = 0.f;
    #define ATTN_STEP(jj) {                                                    \
        int2 ed = edata[off0 + (jj)];                                          \
        float aev = __int_as_float(ed.y);                                      \
        float v = a_s[ed.x * 4 + ht] + adn;                                    \
        v = (v > 0.f ? v : 0.2f * v) * aev;                                    \
        float w = __expf(v - mx);                                              \
        den += w;                                                              \
        half4_t g = *(const half4_t*)&wx[(size_t)ed.x * 128 + c0];             \
        A0 += w * (float)g[0]; A1 += w * (float)g[1];                          \
        A2 += w * (float)g[2]; A3 += w * (float)g[3]; }
    int j = half_;
    for (; j + 2 < cnt; j += 4) { ATTN_STEP(j); ATTN_STEP(j + 2); }
    for (; j < cnt; j += 2) ATTN_STEP(j);
    #undef ATTN_STEP

    den += __shfl_xor(den, 32);
    A0 += __shfl_xor(A0, 32); A1 += __shfl_xor(A1, 32);
    A2 += __shfl_xor(A2, 32); A3 += __shfl_xor(A3, 32);

    if (half_ == 0) {
        float inv = 1.f / (den + 1e-16f);
        float r0 = A0 * inv, r1 = A1 * inv, r2 = A2 * inv, r3 = A3 * inv;
        r0 = r0 > 0.f ? r0 : expm1f(r0);
        r1 = r1 > 0.f ? r1 : expm1f(r1);
        r2 = r2 > 0.f ? r2 : expm1f(r2);
        r3 = r3 > 0.f ? r3 : expm1f(r3);
        if (resid) {
            half4_t rv = *(const half4_t*)((const _Float16*)resid + (size_t)n * 128 + c0);
            r0 += (float)rv[0]; r1 += (float)rv[1];
            r2 += (float)rv[2]; r3 += (float)rv[3];
        }
        half4_t o;
        o[0] = (_Float16)r0; o[1] = (_Float16)r1;
        o[2] = (_Float16)r2; o[3] = (_Float16)r3;
        *(half4_t*)((_Float16*)out + (size_t)n * 128 + c0) = o;
    }
}

// ------------------------------------------------------------------
// Pool: chunked partial sums + atomic flush at segment boundaries.
// ------------------------------------------------------------------
__global__ __launch_bounds__(256) void k_pool2(
    const __half* __restrict__ h, const int* __restrict__ batch,
    float* __restrict__ pooled)
{
    int c = threadIdx.x & 127;
    int hf = threadIdx.x >> 7;
    int n0 = blockIdx.x * 64 + hf * 32;
    if (n0 >= N_NODES) return;
    int nend = n0 + 32; if (nend > N_NODES) nend = N_NODES;

    int g = batch[n0];
    float acc = 0.f;
    for (int n = n0; n < nend; ++n) {
        int bg = batch[n];
        if (bg != g) { atomicAdd(&pooled[g * 128 + c], acc); acc = 0.f; g = bg; }
        acc += __half2float(h[(size_t)n * 128 + c]);
    }
    atomicAdd(&pooled[g * 128 + c], acc);
}

// ------------------------------------------------------------------
// Linear + BatchNorm (+relu)
// ------------------------------------------------------------------
template <int K, int OC>
__global__ __launch_bounds__(256) void k_mlp(
    const float* __restrict__ in, const float* __restrict__ w,
    const float* __restrict__ b, const float* __restrict__ gam,
    const float* __restrict__ bet, float* __restrict__ out, int do_relu)
{
    __shared__ float2 red[256];
    int c = blockIdx.x, g = threadIdx.x;
    float val = b[c];
    #pragma unroll 8
    for (int k = 0; k < K; ++k) val += in[g * K + k] * w[k * OC + c];
    red[g] = make_float2(val, val * val);
    __syncthreads();
    for (int s = 128; s > 0; s >>= 1) {
        if (g < s) { red[g].x += red[g + s].x; red[g].y += red[g + s].y; }
        __syncthreads();
    }
    float mean = red[0].x * (1.f / 256.f);
    float var = red[0].y * (1.f / 256.f) - mean * mean;
    float y = (val - mean) * rsqrtf(var + 1e-5f) * gam[c] + bet[c];
    if (do_relu) y = fmaxf(y, 0.f);
    out[g * OC + c] = y;
}

// ------------------------------------------------------------------
extern "C" void kernel_launch(void* const* d_in, const int* in_sizes, int n_in,
                              void* d_out, int out_size, void* d_ws, size_t ws_size,
                              hipStream_t stream)
{
    const float* x         = (const float*)d_in[0];
    const float* edge_attr = (const float*)d_in[1];
    const float* lin_w     = (const float*)d_in[2];
    const float* lin_b     = (const float*)d_in[3];
    const float* conv_W    = (const float*)d_in[4];
    const float* conv_asrc = (const float*)d_in[5];
    const float* conv_adst = (const float*)d_in[6];
    const float* fc_w1 = (const float*)d_in[7];
    const float* fc_b1 = (const float*)d_in[8];
    const float* bn_g1 = (const float*)d_in[9];
    const float* bn_b1 = (const float*)d_in[10];
    const float* fc_w2 = (const float*)d_in[11];
    const float* fc_b2 = (const float*)d_in[12];
    const float* bn_g2 = (const float*)d_in[13];
    const float* bn_b2 = (const float*)d_in[14];
    const float* fc_w3 = (const float*)d_in[15];
    const float* fc_b3 = (const float*)d_in[16];
    const float* bn_g3 = (const float*)d_in[17];
    const float* bn_b3 = (const float*)d_in[18];
    const int* edge_index = (const int*)d_in[19];
    const int* batch      = (const int*)d_in[20];
    const int* srcp = edge_index;
    const int* dstp = edge_index + N_EDGES;
    float* out = (float*)d_out;

    char* ws = (char*)d_ws;
    __half* x16   = (__half*)ws; ws += (size_t)N_NODES * 128 * 2;
    __half* h_cur = (__half*)ws; ws += (size_t)N_NODES * 128 * 2;
    __half* h_tmp = (__half*)ws; ws += (size_t)N_NODES * 128 * 2;
    __half* wx16  = (__half*)ws; ws += (size_t)N_NODES * 128 * 2;
    float* a_s   = (float*)ws;  ws += (size_t)N_NODES * 4 * 4;
    float* a_d   = (float*)ws;  ws += (size_t)N_NODES * 4 * 4;
    float* pooled= (float*)ws;  ws += (size_t)NGRAPH * 128 * 4;
    float* z1    = (float*)ws;  ws += (size_t)NGRAPH * 64 * 4;
    float* z2    = (float*)ws;  ws += (size_t)NGRAPH * 32 * 4;
    int* deg     = (int*)ws;    ws += (size_t)N_NODES * 4;
    int* offs    = (int*)ws;    ws += (size_t)(N_NODES + 4) * 4;
    int* cursor  = (int*)ws;    ws += (size_t)N_NODES * 4;
    int2* edata  = (int2*)ws;   ws += (size_t)N_EDGES * 8;
    _Float16* wt_g = (_Float16*)ws; ws += (size_t)7 * 16384 * 2;
    int* cs      = (int*)ws;    ws += 64 * 4;
    int* cbase   = (int*)ws;    ws += 64 * 4;

    // --- CSR build + weight prep + casts ---
    k_zero_i<<<(N_NODES + 255) / 256, 256, 0, stream>>>(deg, N_NODES);
    k_deg<<<(N_EDGES + 255) / 256, 256, 0, stream>>>(dstp, deg);
    k_chunksum<<<NCHUNK, 256, 0, stream>>>(deg, cs);
    k_scanbase<<<1, 64, 0, stream>>>(cs, cbase, offs);
    k_scanlocal<<<NCHUNK, 1024, 0, stream>>>(deg, cbase, offs, cursor);
    k_fill<<<(N_EDGES + 255) / 256, 256, 0, stream>>>(srcp, dstp, edge_attr,
                                                      cursor, edata);
    k_wprep<<<(7 * 16384 + 255) / 256, 256, 0, stream>>>(lin_w, conv_W, wt_g);
    k_cast16<<<(N_NODES * 32 + 255) / 256, 256, 0, stream>>>(x, x16, N_NODES * 32);
    k_zero_f<<<(NGRAPH * 128 + 255) / 256, 256, 0, stream>>>(pooled, NGRAPH * 128);

    const int GGRID = (N_NODES + 63) / 64;

    // --- input linear ---
    k_gemm16<<<GGRID, 256, 0, stream>>>(x16, wt_g, lin_b, h_cur, N_NODES,
                                        nullptr, nullptr, nullptr, nullptr);

    // --- 3 residual scatter convs, 2 inner layers each ---
    for (int i = 0; i < 3; ++i) {
        const _Float16* W0 = wt_g + (size_t)(1 + i * 2 + 0) * 16384;
        const _Float16* W1 = wt_g + (size_t)(1 + i * 2 + 1) * 16384;
        const float* as0 = conv_asrc + (size_t)(i * 2 + 0) * 128;
        const float* as1 = conv_asrc + (size_t)(i * 2 + 1) * 128;
        const float* ad0 = conv_adst + (size_t)(i * 2 + 0) * 128;
        const float* ad1 = conv_adst + (size_t)(i * 2 + 1) * 128;

        k_gemm16<<<GGRID, 256, 0, stream>>>(h_cur, W0, nullptr, wx16, N_NODES,
                                            as0, ad0, a_s, a_d);
        k_attn<<<N_NODES / 4, 256, 0, stream>>>(wx16, edata, a_s, a_d,
                                                offs, nullptr, h_tmp);

        k_gemm16<<<GGRID, 256, 0, stream>>>(h_tmp, W1, nullptr, wx16, N_NODES,
                                            as1, ad1, a_s, a_d);
        k_attn<<<N_NODES / 4, 256, 0, stream>>>(wx16, edata, a_s, a_d,
                                                offs, h_cur, h_cur);
    }

    // --- pool + MLP head ---
    k_pool2<<<GGRID, 256, 0, stream>>>(h_cur, batch, pooled);
    k_mlp<128, 64><<<64, 256, 0, stream>>>(pooled, fc_w1, fc_b1, bn_g1, bn_b1, z1, 1);
    k_mlp<64, 32><<<32, 256, 0, stream>>>(z1, fc_w2, fc_b2, bn_g2, bn_b2, z2, 1);
    k_mlp<32, 10><<<10, 256, 0, stream>>>(z2, fc_w3, fc_b3, bn_g3, bn_b3, out, 0);
}

// Round 6
// 556.558 us; speedup vs baseline: 1.1972x; 1.1972x over previous
//
#include <hip/hip_runtime.h>
#include <hip/hip_fp16.h>
#include <math.h>

#define N_NODES 50000
#define N_EDGES 640000
#define NGRAPH  256
#define SCHUNK  1024
#define NCHUNK  49   // ceil(50000/1024)

typedef _Float16 half8_t __attribute__((ext_vector_type(8)));
typedef _Float16 half4_t __attribute__((ext_vector_type(4)));
typedef float floatx4 __attribute__((ext_vector_type(4)));

// ------------------------------------------------------------------
// Weight prep: convert all 7 [128,128] fp32 k-major weights into the
// fp16 transposed+swizzled layout the GEMM stages into LDS:
//   wt[m][n*128 + ((k>>3)^(n&15))*8 + (k&7)]
// ------------------------------------------------------------------
__global__ void k_wprep(const float* __restrict__ lin_w,
                        const float* __restrict__ conv_W,
                        _Float16* __restrict__ wt_g)
{
    int idx = blockIdx.x * 256 + threadIdx.x;
    if (idx >= 7 * 16384) return;
    int m = idx >> 14;
    int r = idx & 16383;
    int k = r >> 7;
    int n = r & 127;
    const float* W = (m == 0) ? lin_w : conv_W + (size_t)(m - 1) * 16384;
    float v = W[(size_t)k * 128 + n];
    int slot = (k >> 3) ^ (n & 15);
    wt_g[(size_t)m * 16384 + n * 128 + slot * 8 + (k & 7)] = (_Float16)v;
}

// ------------------------------------------------------------------
// MFMA GEMM: C16[M,128] = half(A16[M,128] @ W (+bias)).
// W pre-swizzled fp16; staging is a straight vector copy.
// Block 256 = 4 waves; wave computes 16 rows x 128 cols via 8 N-tiles.
// Optional fused attention projections a_s/a_d (fp32).
// ------------------------------------------------------------------
__global__ __launch_bounds__(256) void k_gemm16(
    const __half* __restrict__ A, const _Float16* __restrict__ wt,
    const float* __restrict__ bias, __half* __restrict__ C16, int M,
    const float* __restrict__ asrc, const float* __restrict__ adst,
    float* __restrict__ a_s, float* __restrict__ a_d)
{
    __shared__ _Float16 Wt[128 * 128];   // 32 KB
    int tid = threadIdx.x;
    {
        const float4* wsrc = (const float4*)wt;
        float4* wl = (float4*)Wt;
        #pragma unroll
        for (int r = 0; r < 8; ++r) wl[r * 256 + tid] = wsrc[r * 256 + tid];
    }
    __syncthreads();

    int lane = tid & 63;
    int wv = tid >> 6;
    int r0 = blockIdx.x * 64 + wv * 16;
    int cl = lane & 15;
    int ks = lane >> 4;             // k-chunk group 0..3

    int arow = r0 + cl; if (arow >= M) arow = M - 1;
    const _Float16* Arow = (const _Float16*)A + (size_t)arow * 128 + ks * 8;
    half8_t afrag[4];
    #pragma unroll
    for (int kk = 0; kk < 4; ++kk)
        afrag[kk] = *(const half8_t*)(Arow + kk * 32);

    floatx4 acc[8];
    #pragma unroll
    for (int nt = 0; nt < 8; ++nt) acc[nt] = (floatx4){0.f, 0.f, 0.f, 0.f};

    #pragma unroll
    for (int kk = 0; kk < 4; ++kk) {
        #pragma unroll
        for (int nt = 0; nt < 8; ++nt) {
            int n = nt * 16 + cl;
            int slot = (kk * 4 + ks) ^ cl;
            half8_t bfrag = *(const half8_t*)&Wt[n * 128 + slot * 8];
            acc[nt] = __builtin_amdgcn_mfma_f32_16x16x32_f16(afrag[kk], bfrag, acc[nt], 0, 0, 0);
        }
    }

    int rg = lane >> 4;   // row group for C/D
    #pragma unroll
    for (int nt = 0; nt < 8; ++nt) {
        float bv = bias ? bias[nt * 16 + cl] : 0.f;
        #pragma unroll
        for (int j = 0; j < 4; ++j) {
            int row = r0 + rg * 4 + j;
            if (row < M)
                C16[(size_t)row * 128 + nt * 16 + cl] = __float2half(acc[nt][j] + bv);
        }
    }

    if (a_s) {
        float s[4][4], d[4][4];
        #pragma unroll
        for (int h = 0; h < 4; ++h)
            #pragma unroll
            for (int j = 0; j < 4; ++j) { s[h][j] = 0.f; d[h][j] = 0.f; }
        #pragma unroll
        for (int nt = 0; nt < 8; ++nt) {
            int h = nt >> 1;
            float as = asrc[h * 32 + (nt & 1) * 16 + cl];
            float ad = adst[h * 32 + (nt & 1) * 16 + cl];
            #pragma unroll
            for (int j = 0; j < 4; ++j) {
                s[h][j] += acc[nt][j] * as;
                d[h][j] += acc[nt][j] * ad;
            }
        }
        #pragma unroll
        for (int h = 0; h < 4; ++h)
            #pragma unroll
            for (int j = 0; j < 4; ++j)
                #pragma unroll
                for (int k = 1; k < 16; k <<= 1) {
                    s[h][j] += __shfl_xor(s[h][j], k);
                    d[h][j] += __shfl_xor(d[h][j], k);
                }
        if (cl == 0) {
            #pragma unroll
            for (int j = 0; j < 4; ++j) {
                int row = r0 + rg * 4 + j;
                if (row < M) {
                    #pragma unroll
                    for (int h = 0; h < 4; ++h) {
                        a_s[row * 4 + h] = s[h][j];
                        a_d[row * 4 + h] = d[h][j];
                    }
                }
            }
        }
    }
}

// ------------------------------------------------------------------
__global__ void k_cast16(const float* __restrict__ in, __half* __restrict__ out, int n4) {
    int i = blockIdx.x * blockDim.x + threadIdx.x;
    if (i < n4) {
        float4 v = ((const float4*)in)[i];
        __half2 a = __floats2half2_rn(v.x, v.y);
        __half2 b = __floats2half2_rn(v.z, v.w);
        ((__half2*)out)[i * 2] = a;
        ((__half2*)out)[i * 2 + 1] = b;
    }
}

__global__ void k_zero_i(int* p, int n) {
    int i = blockIdx.x * blockDim.x + threadIdx.x;
    if (i < n) p[i] = 0;
}

__global__ void k_zero_f(float* p, int n) {
    int i = blockIdx.x * blockDim.x + threadIdx.x;
    if (i < n) p[i] = 0.f;
}

// ------------------------------------------------------------------
// CSR build; k_fill writes packed (src, ea) int2 directly in CSR order.
// ------------------------------------------------------------------
__global__ void k_deg(const int* __restrict__ dst, int* deg) {
    int e = blockIdx.x * blockDim.x + threadIdx.x;
    if (e < N_EDGES) atomicAdd(&deg[dst[e]], 1);
}

__global__ __launch_bounds__(256) void k_chunksum(const int* __restrict__ deg, int* cs) {
    __shared__ int r[256];
    int b = blockIdx.x;
    int acc = 0;
    for (int i = threadIdx.x; i < SCHUNK; i += 256) {
        int idx = b * SCHUNK + i;
        if (idx < N_NODES) acc += deg[idx];
    }
    r[threadIdx.x] = acc; __syncthreads();
    for (int s = 128; s > 0; s >>= 1) {
        if (threadIdx.x < s) r[threadIdx.x] += r[threadIdx.x + s];
        __syncthreads();
    }
    if (threadIdx.x == 0) cs[b] = r[0];
}

__global__ void k_scanbase(const int* cs, int* base, int* offs) {
    if (threadIdx.x == 0) {
        int run = 0;
        for (int b = 0; b < NCHUNK; ++b) { base[b] = run; run += cs[b]; }
        offs[N_NODES] = run;
    }
}

__global__ __launch_bounds__(1024) void k_scanlocal(
    const int* __restrict__ deg, const int* __restrict__ base,
    int* offs, int* cursor)
{
    __shared__ int s[1024];
    int b = blockIdx.x, t = threadIdx.x;
    int idx = b * SCHUNK + t;
    int d = (idx < N_NODES) ? deg[idx] : 0;
    s[t] = d; __syncthreads();
    for (int off = 1; off < 1024; off <<= 1) {
        int v = (t >= off) ? s[t - off] : 0;
        __syncthreads();
        s[t] += v; __syncthreads();
    }
    if (idx < N_NODES) {
        int ex = s[t] - d + base[b];
        offs[idx] = ex; cursor[idx] = ex;
    }
}

__global__ void k_fill(const int* __restrict__ src, const int* __restrict__ dst,
                       const float* __restrict__ ea, int* cursor,
                       int2* __restrict__ edata)
{
    int e = blockIdx.x * blockDim.x + threadIdx.x;
    if (e < N_EDGES) {
        int p = atomicAdd(&cursor[dst[e]], 1);
        edata[p] = make_int2(src[e], __float_as_int(ea[e]));
    }
}

// ------------------------------------------------------------------
// Alpha: per-node softmax over incident edges, 16 lanes per node.
// Pass 1: gather a_s once, compute logits, cache fp16 in walpha,
// track per-head max. Pass 2: re-read logits SEQUENTIALLY, exp,
// rewrite walpha as unnormalized weights, reduce denom.
// ------------------------------------------------------------------
__global__ __launch_bounds__(256) void k_alpha(
    const float* __restrict__ a_s, const float* __restrict__ a_d,
    const int2* __restrict__ edata, const int* __restrict__ offs,
    __half2* __restrict__ walpha, float* __restrict__ denom)
{
    int l = threadIdx.x & 15;
    int n = blockIdx.x * 16 + (threadIdx.x >> 4);
    int off0 = offs[n], off1 = offs[n + 1];
    float4 adn = *(const float4*)&a_d[n * 4];

    float m0 = -3e38f, m1 = -3e38f, m2 = -3e38f, m3 = -3e38f;
    for (int i = off0 + l; i < off1; i += 16) {
        int2 ed = edata[i];
        float aev = __int_as_float(ed.y);
        float4 as4 = *(const float4*)&a_s[ed.x * 4];
        float v0 = as4.x + adn.x; v0 = (v0 > 0.f ? v0 : 0.2f * v0) * aev;
        float v1 = as4.y + adn.y; v1 = (v1 > 0.f ? v1 : 0.2f * v1) * aev;
        float v2 = as4.z + adn.z; v2 = (v2 > 0.f ? v2 : 0.2f * v2) * aev;
        float v3 = as4.w + adn.w; v3 = (v3 > 0.f ? v3 : 0.2f * v3) * aev;
        walpha[(size_t)i * 2]     = __floats2half2_rn(v0, v1);
        walpha[(size_t)i * 2 + 1] = __floats2half2_rn(v2, v3);
        m0 = fmaxf(m0, v0); m1 = fmaxf(m1, v1);
        m2 = fmaxf(m2, v2); m3 = fmaxf(m3, v3);
    }
    #pragma unroll
    for (int k = 1; k < 16; k <<= 1) {
        m0 = fmaxf(m0, __shfl_xor(m0, k));
        m1 = fmaxf(m1, __shfl_xor(m1, k));
        m2 = fmaxf(m2, __shfl_xor(m2, k));
        m3 = fmaxf(m3, __shfl_xor(m3, k));
    }

    float s0 = 0.f, s1 = 0.f, s2 = 0.f, s3 = 0.f;
    for (int i = off0 + l; i < off1; i += 16) {
        float2 va = __half22float2(walpha[(size_t)i * 2]);
        float2 vb = __half22float2(walpha[(size_t)i * 2 + 1]);
        float w0 = __expf(va.x - m0), w1 = __expf(va.y - m1);
        float w2 = __expf(vb.x - m2), w3 = __expf(vb.y - m3);
        walpha[(size_t)i * 2]     = __floats2half2_rn(w0, w1);
        walpha[(size_t)i * 2 + 1] = __floats2half2_rn(w2, w3);
        s0 += w0; s1 += w1; s2 += w2; s3 += w3;
    }
    #pragma unroll
    for (int k = 1; k < 16; k <<= 1) {
        s0 += __shfl_xor(s0, k); s1 += __shfl_xor(s1, k);
        s2 += __shfl_xor(s2, k); s3 += __shfl_xor(s3, k);
    }
    if (l == 0) *(float4*)&denom[n * 4] = make_float4(s0, s1, s2, s3);
}

// ------------------------------------------------------------------
// Gather: one wave per destination node. 4 edge slots (q = lane>>4),
// 16 lanes per edge, 16B (half8) per lane. Unroll-2 => 8 independent
// row gathers in flight per wave. Reduce via shfl_xor(16,32).
// ------------------------------------------------------------------
__global__ __launch_bounds__(256) void k_gather(
    const __half* __restrict__ wx16, const int2* __restrict__ edata,
    const __half* __restrict__ walpha, const float* __restrict__ denom,
    const int* __restrict__ offs, const __half* __restrict__ resid,
    __half* __restrict__ out)
{
    int lane = threadIdx.x & 63;
    int n = blockIdx.x * 4 + (threadIdx.x >> 6);
    int q = lane >> 4;        // edge slot 0..3
    int cl = lane & 15;       // col lane: 8 cols each
    int c0 = cl * 8;
    int ht = cl >> 2;         // head of these 8 cols
    int off0 = offs[n], off1 = offs[n + 1];
    int cnt = off1 - off0;
    const _Float16* wx = (const _Float16*)wx16;

    float a[8];
    #pragma unroll
    for (int k = 0; k < 8; ++k) a[k] = 0.f;

    #define GSTEP(jj) {                                                        \
        int e = off0 + (jj);                                                   \
        int s = edata[e].x;                                                    \
        float w = __half2float(walpha[(size_t)e * 4 + ht]);                    \
        half8_t g = *(const half8_t*)&wx[(size_t)s * 128 + c0];                \
        a[0] += w * (float)g[0]; a[1] += w * (float)g[1];                      \
        a[2] += w * (float)g[2]; a[3] += w * (float)g[3];                      \
        a[4] += w * (float)g[4]; a[5] += w * (float)g[5];                      \
        a[6] += w * (float)g[6]; a[7] += w * (float)g[7]; }

    int j = q;
    for (; j + 4 < cnt; j += 8) { GSTEP(j); GSTEP(j + 4); }
    if (j < cnt) GSTEP(j);
    #undef GSTEP

    #pragma unroll
    for (int k = 0; k < 8; ++k) {
        a[k] += __shfl_xor(a[k], 16);
        a[k] += __shfl_xor(a[k], 32);
    }

    if (q == 0) {
        float inv = 1.f / (denom[n * 4 + ht] + 1e-16f);
        half8_t rv;
        if (resid) rv = *(const half8_t*)((const _Float16*)resid + (size_t)n * 128 + c0);
        half8_t o;
        #pragma unroll
        for (int k = 0; k < 8; ++k) {
            float r = a[k] * inv;
            r = r > 0.f ? r : expm1f(r);
            if (resid) r += (float)rv[k];
            o[k] = (_Float16)r;
        }
        *(half8_t*)((_Float16*)out + (size_t)n * 128 + c0) = o;
    }
}

// ------------------------------------------------------------------
// Pool: chunked partial sums + atomic flush at segment boundaries.
// ------------------------------------------------------------------
__global__ __launch_bounds__(256) void k_pool2(
    const __half* __restrict__ h, const int* __restrict__ batch,
    float* __restrict__ pooled)
{
    int c = threadIdx.x & 127;
    int hf = threadIdx.x >> 7;
    int n0 = blockIdx.x * 64 + hf * 32;
    if (n0 >= N_NODES) return;
    int nend = n0 + 32; if (nend > N_NODES) nend = N_NODES;

    int g = batch[n0];
    float acc = 0.f;
    for (int n = n0; n < nend; ++n) {
        int bg = batch[n];
        if (bg != g) { atomicAdd(&pooled[g * 128 + c], acc); acc = 0.f; g = bg; }
        acc += __half2float(h[(size_t)n * 128 + c]);
    }
    atomicAdd(&pooled[g * 128 + c], acc);
}

// ------------------------------------------------------------------
// Linear + BatchNorm (+relu)
// ------------------------------------------------------------------
template <int K, int OC>
__global__ __launch_bounds__(256) void k_mlp(
    const float* __restrict__ in, const float* __restrict__ w,
    const float* __restrict__ b, const float* __restrict__ gam,
    const float* __restrict__ bet, float* __restrict__ out, int do_relu)
{
    __shared__ float2 red[256];
    int c = blockIdx.x, g = threadIdx.x;
    float val = b[c];
    #pragma unroll 8
    for (int k = 0; k < K; ++k) val += in[g * K + k] * w[k * OC + c];
    red[g] = make_float2(val, val * val);
    __syncthreads();
    for (int s = 128; s > 0; s >>= 1) {
        if (g < s) { red[g].x += red[g + s].x; red[g].y += red[g + s].y; }
        __syncthreads();
    }
    float mean = red[0].x * (1.f / 256.f);
    float var = red[0].y * (1.f / 256.f) - mean * mean;
    float y = (val - mean) * rsqrtf(var + 1e-5f) * gam[c] + bet[c];
    if (do_relu) y = fmaxf(y, 0.f);
    out[g * OC + c] = y;
}

// ------------------------------------------------------------------
extern "C" void kernel_launch(void* const* d_in, const int* in_sizes, int n_in,
                              void* d_out, int out_size, void* d_ws, size_t ws_size,
                              hipStream_t stream)
{
    const float* x         = (const float*)d_in[0];
    const float* edge_attr = (const float*)d_in[1];
    const float* lin_w     = (const float*)d_in[2];
    const float* lin_b     = (const float*)d_in[3];
    const float* conv_W    = (const float*)d_in[4];
    const float* conv_asrc = (const float*)d_in[5];
    const float* conv_adst = (const float*)d_in[6];
    const float* fc_w1 = (const float*)d_in[7];
    const float* fc_b1 = (const float*)d_in[8];
    const float* bn_g1 = (const float*)d_in[9];
    const float* bn_b1 = (const float*)d_in[10];
    const float* fc_w2 = (const float*)d_in[11];
    const float* fc_b2 = (const float*)d_in[12];
    const float* bn_g2 = (const float*)d_in[13];
    const float* bn_b2 = (const float*)d_in[14];
    const float* fc_w3 = (const float*)d_in[15];
    const float* fc_b3 = (const float*)d_in[16];
    const float* bn_g3 = (const float*)d_in[17];
    const float* bn_b3 = (const float*)d_in[18];
    const int* edge_index = (const int*)d_in[19];
    const int* batch      = (const int*)d_in[20];
    const int* srcp = edge_index;
    const int* dstp = edge_index + N_EDGES;
    float* out = (float*)d_out;

    char* ws = (char*)d_ws;
    __half* x16   = (__half*)ws; ws += (size_t)N_NODES * 128 * 2;
    __half* h_cur = (__half*)ws; ws += (size_t)N_NODES * 128 * 2;
    __half* h_tmp = (__half*)ws; ws += (size_t)N_NODES * 128 * 2;
    __half* wx16  = (__half*)ws; ws += (size_t)N_NODES * 128 * 2;
    float* a_s   = (float*)ws;  ws += (size_t)N_NODES * 4 * 4;
    float* a_d   = (float*)ws;  ws += (size_t)N_NODES * 4 * 4;
    float* denom = (float*)ws;  ws += (size_t)N_NODES * 4 * 4;
    float* pooled= (float*)ws;  ws += (size_t)NGRAPH * 128 * 4;
    float* z1    = (float*)ws;  ws += (size_t)NGRAPH * 64 * 4;
    float* z2    = (float*)ws;  ws += (size_t)NGRAPH * 32 * 4;
    int* deg     = (int*)ws;    ws += (size_t)N_NODES * 4;
    int* offs    = (int*)ws;    ws += (size_t)(N_NODES + 4) * 4;
    int* cursor  = (int*)ws;    ws += (size_t)N_NODES * 4;
    int2* edata  = (int2*)ws;   ws += (size_t)N_EDGES * 8;
    __half2* walpha = (__half2*)ws; ws += (size_t)N_EDGES * 8;
    _Float16* wt_g = (_Float16*)ws; ws += (size_t)7 * 16384 * 2;
    int* cs      = (int*)ws;    ws += 64 * 4;
    int* cbase   = (int*)ws;    ws += 64 * 4;

    // --- CSR build + weight prep + casts ---
    k_zero_i<<<(N_NODES + 255) / 256, 256, 0, stream>>>(deg, N_NODES);
    k_deg<<<(N_EDGES + 255) / 256, 256, 0, stream>>>(dstp, deg);
    k_chunksum<<<NCHUNK, 256, 0, stream>>>(deg, cs);
    k_scanbase<<<1, 64, 0, stream>>>(cs, cbase, offs);
    k_scanlocal<<<NCHUNK, 1024, 0, stream>>>(deg, cbase, offs, cursor);
    k_fill<<<(N_EDGES + 255) / 256, 256, 0, stream>>>(srcp, dstp, edge_attr,
                                                      cursor, edata);
    k_wprep<<<(7 * 16384 + 255) / 256, 256, 0, stream>>>(lin_w, conv_W, wt_g);
    k_cast16<<<(N_NODES * 32 + 255) / 256, 256, 0, stream>>>(x, x16, N_NODES * 32);
    k_zero_f<<<(NGRAPH * 128 + 255) / 256, 256, 0, stream>>>(pooled, NGRAPH * 128);

    const int GGRID = (N_NODES + 63) / 64;

    // --- input linear ---
    k_gemm16<<<GGRID, 256, 0, stream>>>(x16, wt_g, lin_b, h_cur, N_NODES,
                                        nullptr, nullptr, nullptr, nullptr);

    // --- 3 residual scatter convs, 2 inner layers each ---
    for (int i = 0; i < 3; ++i) {
        const _Float16* W0 = wt_g + (size_t)(1 + i * 2 + 0) * 16384;
        const _Float16* W1 = wt_g + (size_t)(1 + i * 2 + 1) * 16384;
        const float* as0 = conv_asrc + (size_t)(i * 2 + 0) * 128;
        const float* as1 = conv_asrc + (size_t)(i * 2 + 1) * 128;
        const float* ad0 = conv_adst + (size_t)(i * 2 + 0) * 128;
        const float* ad1 = conv_adst + (size_t)(i * 2 + 1) * 128;

        k_gemm16<<<GGRID, 256, 0, stream>>>(h_cur, W0, nullptr, wx16, N_NODES,
                                            as0, ad0, a_s, a_d);
        k_alpha<<<N_NODES / 16, 256, 0, stream>>>(a_s, a_d, edata, offs,
                                                  walpha, denom);
        k_gather<<<N_NODES / 4, 256, 0, stream>>>(wx16, edata, (const __half*)walpha,
                                                  denom, offs, nullptr, h_tmp);

        k_gemm16<<<GGRID, 256, 0, stream>>>(h_tmp, W1, nullptr, wx16, N_NODES,
                                            as1, ad1, a_s, a_d);
        k_alpha<<<N_NODES / 16, 256, 0, stream>>>(a_s, a_d, edata, offs,
                                                  walpha, denom);
        k_gather<<<N_NODES / 4, 256, 0, stream>>>(wx16, edata, (const __half*)walpha,
                                                  denom, offs, h_cur, h_cur);
    }

    // --- pool + MLP head ---
    k_pool2<<<GGRID, 256, 0, stream>>>(h_cur, batch, pooled);
    k_mlp<128, 64><<<64, 256, 0, stream>>>(pooled, fc_w1, fc_b1, bn_g1, bn_b1, z1, 1);
    k_mlp<64, 32><<<32, 256, 0, stream>>>(z1, fc_w2, fc_b2, bn_g2, bn_b2, z2, 1);
    k_mlp<32, 10><<<10, 256, 0, stream>>>(z2, fc_w3, fc_b3, bn_g3, bn_b3, out, 0);
}

// Round 7
// 527.818 us; speedup vs baseline: 1.2624x; 1.0545x over previous
//
#include <hip/hip_runtime.h>
#include <hip/hip_fp16.h>
#include <math.h>

#define N_NODES 50000
#define N_EDGES 640000
#define NGRAPH  256
#define SCHUNK  1024
#define NCHUNK  49   // ceil(50000/1024)

typedef _Float16 half8_t __attribute__((ext_vector_type(8)));
typedef float floatx4 __attribute__((ext_vector_type(4)));

// ------------------------------------------------------------------
// Weight prep: convert all 7 [128,128] fp32 k-major weights into the
// fp16 transposed+swizzled layout the GEMM stages into LDS:
//   wt[m][n*128 + ((k>>3)^(n&15))*8 + (k&7)]
// ------------------------------------------------------------------
__global__ void k_wprep(const float* __restrict__ lin_w,
                        const float* __restrict__ conv_W,
                        _Float16* __restrict__ wt_g)
{
    int idx = blockIdx.x * 256 + threadIdx.x;
    if (idx >= 7 * 16384) return;
    int m = idx >> 14;
    int r = idx & 16383;
    int k = r >> 7;
    int n = r & 127;
    const float* W = (m == 0) ? lin_w : conv_W + (size_t)(m - 1) * 16384;
    float v = W[(size_t)k * 128 + n];
    int slot = (k >> 3) ^ (n & 15);
    wt_g[(size_t)m * 16384 + n * 128 + slot * 8 + (k & 7)] = (_Float16)v;
}

// ------------------------------------------------------------------
// MFMA GEMM: C16[M,128] = half(A16[M,128] @ W (+bias)).
// W pre-swizzled fp16; staging is a straight vector copy.
// Block 256 = 4 waves; wave computes 16 rows x 128 cols via 8 N-tiles.
// Optional fused attention projections a_s/a_d (fp32).
// ------------------------------------------------------------------
__global__ __launch_bounds__(256) void k_gemm16(
    const __half* __restrict__ A, const _Float16* __restrict__ wt,
    const float* __restrict__ bias, __half* __restrict__ C16, int M,
    const float* __restrict__ asrc, const float* __restrict__ adst,
    float* __restrict__ a_s, float* __restrict__ a_d)
{
    __shared__ _Float16 Wt[128 * 128];   // 32 KB
    int tid = threadIdx.x;
    {
        const float4* wsrc = (const float4*)wt;
        float4* wl = (float4*)Wt;
        #pragma unroll
        for (int r = 0; r < 8; ++r) wl[r * 256 + tid] = wsrc[r * 256 + tid];
    }
    __syncthreads();

    int lane = tid & 63;
    int wv = tid >> 6;
    int r0 = blockIdx.x * 64 + wv * 16;
    int cl = lane & 15;
    int ks = lane >> 4;             // k-chunk group 0..3

    int arow = r0 + cl; if (arow >= M) arow = M - 1;
    const _Float16* Arow = (const _Float16*)A + (size_t)arow * 128 + ks * 8;
    half8_t afrag[4];
    #pragma unroll
    for (int kk = 0; kk < 4; ++kk)
        afrag[kk] = *(const half8_t*)(Arow + kk * 32);

    floatx4 acc[8];
    #pragma unroll
    for (int nt = 0; nt < 8; ++nt) acc[nt] = (floatx4){0.f, 0.f, 0.f, 0.f};

    #pragma unroll
    for (int kk = 0; kk < 4; ++kk) {
        #pragma unroll
        for (int nt = 0; nt < 8; ++nt) {
            int n = nt * 16 + cl;
            int slot = (kk * 4 + ks) ^ cl;
            half8_t bfrag = *(const half8_t*)&Wt[n * 128 + slot * 8];
            acc[nt] = __builtin_amdgcn_mfma_f32_16x16x32_f16(afrag[kk], bfrag, acc[nt], 0, 0, 0);
        }
    }

    int rg = lane >> 4;   // row group for C/D
    #pragma unroll
    for (int nt = 0; nt < 8; ++nt) {
        float bv = bias ? bias[nt * 16 + cl] : 0.f;
        #pragma unroll
        for (int j = 0; j < 4; ++j) {
            int row = r0 + rg * 4 + j;
            if (row < M)
                C16[(size_t)row * 128 + nt * 16 + cl] = __float2half(acc[nt][j] + bv);
        }
    }

    if (a_s) {
        float s[4][4], d[4][4];
        #pragma unroll
        for (int h = 0; h < 4; ++h)
            #pragma unroll
            for (int j = 0; j < 4; ++j) { s[h][j] = 0.f; d[h][j] = 0.f; }
        #pragma unroll
        for (int nt = 0; nt < 8; ++nt) {
            int h = nt >> 1;
            float as = asrc[h * 32 + (nt & 1) * 16 + cl];
            float ad = adst[h * 32 + (nt & 1) * 16 + cl];
            #pragma unroll
            for (int j = 0; j < 4; ++j) {
                s[h][j] += acc[nt][j] * as;
                d[h][j] += acc[nt][j] * ad;
            }
        }
        #pragma unroll
        for (int h = 0; h < 4; ++h)
            #pragma unroll
            for (int j = 0; j < 4; ++j)
                #pragma unroll
                for (int k = 1; k < 16; k <<= 1) {
                    s[h][j] += __shfl_xor(s[h][j], k);
                    d[h][j] += __shfl_xor(d[h][j], k);
                }
        if (cl == 0) {
            #pragma unroll
            for (int j = 0; j < 4; ++j) {
                int row = r0 + rg * 4 + j;
                if (row < M) {
                    #pragma unroll
                    for (int h = 0; h < 4; ++h) {
                        a_s[row * 4 + h] = s[h][j];
                        a_d[row * 4 + h] = d[h][j];
                    }
                }
            }
        }
    }
}

// ------------------------------------------------------------------
__global__ void k_cast16(const float* __restrict__ in, __half* __restrict__ out, int n4) {
    int i = blockIdx.x * blockDim.x + threadIdx.x;
    if (i < n4) {
        float4 v = ((const float4*)in)[i];
        __half2 a = __floats2half2_rn(v.x, v.y);
        __half2 b = __floats2half2_rn(v.z, v.w);
        ((__half2*)out)[i * 2] = a;
        ((__half2*)out)[i * 2 + 1] = b;
    }
}

__global__ void k_zero_i(int* p, int n) {
    int i = blockIdx.x * blockDim.x + threadIdx.x;
    if (i < n) p[i] = 0;
}

__global__ void k_zero_f(float* p, int n) {
    int i = blockIdx.x * blockDim.x + threadIdx.x;
    if (i < n) p[i] = 0.f;
}

// ------------------------------------------------------------------
// CSR build; k_fill writes packed (src, ea) int2 directly in CSR order.
// ------------------------------------------------------------------
__global__ void k_deg(const int* __restrict__ dst, int* deg) {
    int e = blockIdx.x * blockDim.x + threadIdx.x;
    if (e < N_EDGES) atomicAdd(&deg[dst[e]], 1);
}

__global__ __launch_bounds__(256) void k_chunksum(const int* __restrict__ deg, int* cs) {
    __shared__ int r[256];
    int b = blockIdx.x;
    int acc = 0;
    for (int i = threadIdx.x; i < SCHUNK; i += 256) {
        int idx = b * SCHUNK + i;
        if (idx < N_NODES) acc += deg[idx];
    }
    r[threadIdx.x] = acc; __syncthreads();
    for (int s = 128; s > 0; s >>= 1) {
        if (threadIdx.x < s) r[threadIdx.x] += r[threadIdx.x + s];
        __syncthreads();
    }
    if (threadIdx.x == 0) cs[b] = r[0];
}

__global__ void k_scanbase(const int* cs, int* base, int* offs) {
    if (threadIdx.x == 0) {
        int run = 0;
        for (int b = 0; b < NCHUNK; ++b) { base[b] = run; run += cs[b]; }
        offs[N_NODES] = run;
    }
}

__global__ __launch_bounds__(1024) void k_scanlocal(
    const int* __restrict__ deg, const int* __restrict__ base,
    int* offs, int* cursor)
{
    __shared__ int s[1024];
    int b = blockIdx.x, t = threadIdx.x;
    int idx = b * SCHUNK + t;
    int d = (idx < N_NODES) ? deg[idx] : 0;
    s[t] = d; __syncthreads();
    for (int off = 1; off < 1024; off <<= 1) {
        int v = (t >= off) ? s[t - off] : 0;
        __syncthreads();
        s[t] += v; __syncthreads();
    }
    if (idx < N_NODES) {
        int ex = s[t] - d + base[b];
        offs[idx] = ex; cursor[idx] = ex;
    }
}

__global__ void k_fill(const int* __restrict__ src, const int* __restrict__ dst,
                       const float* __restrict__ ea, int* cursor,
                       int2* __restrict__ edata)
{
    int e = blockIdx.x * blockDim.x + threadIdx.x;
    if (e < N_EDGES) {
        int p = atomicAdd(&cursor[dst[e]], 1);
        edata[p] = make_int2(src[e], __float_as_int(ea[e]));
    }
}

// ------------------------------------------------------------------
// Fused online-softmax attention aggregation. One wave per node.
// Per 32-edge chunk:
//  phase A (lane = 4*edge+head): gather a_s once per edge*head,
//    compute logit, chunk-max via shfl reduce, online-rescale den/acc,
//    w = exp(v - m).
//  phase B (lane = 16*slot+col): pull (w, src) from phase-A lanes via
//    __shfl, gather wx row (half8 per lane), accumulate.
// No LDS, no barriers, logits computed exactly once.
// ------------------------------------------------------------------
__global__ __launch_bounds__(256) void k_attn2(
    const __half* __restrict__ wx16, const int2* __restrict__ edata,
    const float* __restrict__ a_s, const float* __restrict__ a_d,
    const int* __restrict__ offs, const __half* __restrict__ resid,
    __half* __restrict__ out)
{
    int lane = threadIdx.x & 63;
    int n = blockIdx.x * 4 + (threadIdx.x >> 6);
    int off0 = offs[n], off1 = offs[n + 1];
    int cnt = off1 - off0;

    int h  = lane & 3;        // phase A: head
    int eA = lane >> 2;       // phase A: edge-in-sweep 0..15
    int q  = lane >> 4;       // phase B: edge slot 0..3
    int cl = lane & 15;       // phase B: col lane (8 cols)
    int c0 = cl * 8;
    int ht = cl >> 2;         // phase B: head of these cols

    float adn = a_d[n * 4 + h];
    const _Float16* wx = (const _Float16*)wx16;

    float m = -3e38f, den = 0.f;
    float acc[8];
    #pragma unroll
    for (int k = 0; k < 8; ++k) acc[k] = 0.f;

    for (int c = 0; c < cnt; c += 32) {
        // ---- phase A ----
        float v0 = -3e38f, v1 = -3e38f;
        int s0 = 0, s1 = 0;
        int e0 = c + eA, e1 = c + 16 + eA;
        if (e0 < cnt) {
            int2 ed = edata[off0 + e0];
            s0 = ed.x;
            float t = a_s[ed.x * 4 + h] + adn;
            v0 = (t > 0.f ? t : 0.2f * t) * __int_as_float(ed.y);
        }
        if (e1 < cnt) {
            int2 ed = edata[off0 + e1];
            s1 = ed.x;
            float t = a_s[ed.x * 4 + h] + adn;
            v1 = (t > 0.f ? t : 0.2f * t) * __int_as_float(ed.y);
        }
        float cm = fmaxf(v0, v1);
        cm = fmaxf(cm, __shfl_xor(cm, 4));
        cm = fmaxf(cm, __shfl_xor(cm, 8));
        cm = fmaxf(cm, __shfl_xor(cm, 16));
        cm = fmaxf(cm, __shfl_xor(cm, 32));
        float newm = fmaxf(m, cm);
        float f = __expf(m - newm);      // finite sentinels: no NaN
        m = newm;
        float w0 = __expf(v0 - m);       // invalid edges underflow to 0
        float w1 = __expf(v1 - m);
        den = den * f + w0 + w1;
        float fB = __shfl(f, ht);        // lane ht holds head ht's factor
        #pragma unroll
        for (int k = 0; k < 8; ++k) acc[k] *= fB;

        // ---- phase B ----
        #pragma unroll
        for (int t = 0; t < 8; ++t) {
            int el = q + 4 * t;                      // 0..31
            int srcl = ((el & 15) << 2) + ht;        // phase-A lane holding (el, ht)
            float w = __shfl(t < 4 ? w0 : w1, srcl);
            int   s = __shfl(t < 4 ? s0 : s1, srcl);
            if (c + el < cnt) {
                half8_t g = *(const half8_t*)&wx[(size_t)s * 128 + c0];
                #pragma unroll
                for (int k = 0; k < 8; ++k) acc[k] += w * (float)g[k];
            }
        }
    }

    // final reductions
    den += __shfl_xor(den, 4);
    den += __shfl_xor(den, 8);
    den += __shfl_xor(den, 16);
    den += __shfl_xor(den, 32);
    #pragma unroll
    for (int k = 0; k < 8; ++k) {
        acc[k] += __shfl_xor(acc[k], 16);
        acc[k] += __shfl_xor(acc[k], 32);
    }
    float denB = __shfl(den, ht);   // head-ht denominator (before divergence)

    if (q == 0) {
        float inv = 1.f / (denB + 1e-16f);
        half8_t rv;
        if (resid) rv = *(const half8_t*)((const _Float16*)resid + (size_t)n * 128 + c0);
        half8_t o;
        #pragma unroll
        for (int k = 0; k < 8; ++k) {
            float r = acc[k] * inv;
            r = r > 0.f ? r : expm1f(r);
            if (resid) r += (float)rv[k];
            o[k] = (_Float16)r;
        }
        *(half8_t*)((_Float16*)out + (size_t)n * 128 + c0) = o;
    }
}

// ------------------------------------------------------------------
// Pool: chunked partial sums + atomic flush at segment boundaries.
// ------------------------------------------------------------------
__global__ __launch_bounds__(256) void k_pool2(
    const __half* __restrict__ h, const int* __restrict__ batch,
    float* __restrict__ pooled)
{
    int c = threadIdx.x & 127;
    int hf = threadIdx.x >> 7;
    int n0 = blockIdx.x * 64 + hf * 32;
    if (n0 >= N_NODES) return;
    int nend = n0 + 32; if (nend > N_NODES) nend = N_NODES;

    int g = batch[n0];
    float acc = 0.f;
    for (int n = n0; n < nend; ++n) {
        int bg = batch[n];
        if (bg != g) { atomicAdd(&pooled[g * 128 + c], acc); acc = 0.f; g = bg; }
        acc += __half2float(h[(size_t)n * 128 + c]);
    }
    atomicAdd(&pooled[g * 128 + c], acc);
}

// ------------------------------------------------------------------
// Linear + BatchNorm (+relu)
// ------------------------------------------------------------------
template <int K, int OC>
__global__ __launch_bounds__(256) void k_mlp(
    const float* __restrict__ in, const float* __restrict__ w,
    const float* __restrict__ b, const float* __restrict__ gam,
    const float* __restrict__ bet, float* __restrict__ out, int do_relu)
{
    __shared__ float2 red[256];
    int c = blockIdx.x, g = threadIdx.x;
    float val = b[c];
    #pragma unroll 8
    for (int k = 0; k < K; ++k) val += in[g * K + k] * w[k * OC + c];
    red[g] = make_float2(val, val * val);
    __syncthreads();
    for (int s = 128; s > 0; s >>= 1) {
        if (g < s) { red[g].x += red[g + s].x; red[g].y += red[g + s].y; }
        __syncthreads();
    }
    float mean = red[0].x * (1.f / 256.f);
    float var = red[0].y * (1.f / 256.f) - mean * mean;
    float y = (val - mean) * rsqrtf(var + 1e-5f) * gam[c] + bet[c];
    if (do_relu) y = fmaxf(y, 0.f);
    out[g * OC + c] = y;
}

// ------------------------------------------------------------------
extern "C" void kernel_launch(void* const* d_in, const int* in_sizes, int n_in,
                              void* d_out, int out_size, void* d_ws, size_t ws_size,
                              hipStream_t stream)
{
    const float* x         = (const float*)d_in[0];
    const float* edge_attr = (const float*)d_in[1];
    const float* lin_w     = (const float*)d_in[2];
    const float* lin_b     = (const float*)d_in[3];
    const float* conv_W    = (const float*)d_in[4];
    const float* conv_asrc = (const float*)d_in[5];
    const float* conv_adst = (const float*)d_in[6];
    const float* fc_w1 = (const float*)d_in[7];
    const float* fc_b1 = (const float*)d_in[8];
    const float* bn_g1 = (const float*)d_in[9];
    const float* bn_b1 = (const float*)d_in[10];
    const float* fc_w2 = (const float*)d_in[11];
    const float* fc_b2 = (const float*)d_in[12];
    const float* bn_g2 = (const float*)d_in[13];
    const float* bn_b2 = (const float*)d_in[14];
    const float* fc_w3 = (const float*)d_in[15];
    const float* fc_b3 = (const float*)d_in[16];
    const float* bn_g3 = (const float*)d_in[17];
    const float* bn_b3 = (const float*)d_in[18];
    const int* edge_index = (const int*)d_in[19];
    const int* batch      = (const int*)d_in[20];
    const int* srcp = edge_index;
    const int* dstp = edge_index + N_EDGES;
    float* out = (float*)d_out;

    char* ws = (char*)d_ws;
    __half* x16   = (__half*)ws; ws += (size_t)N_NODES * 128 * 2;
    __half* h_cur = (__half*)ws; ws += (size_t)N_NODES * 128 * 2;
    __half* h_tmp = (__half*)ws; ws += (size_t)N_NODES * 128 * 2;
    __half* wx16  = (__half*)ws; ws += (size_t)N_NODES * 128 * 2;
    float* a_s   = (float*)ws;  ws += (size_t)N_NODES * 4 * 4;
    float* a_d   = (float*)ws;  ws += (size_t)N_NODES * 4 * 4;
    float* pooled= (float*)ws;  ws += (size_t)NGRAPH * 128 * 4;
    float* z1    = (float*)ws;  ws += (size_t)NGRAPH * 64 * 4;
    float* z2    = (float*)ws;  ws += (size_t)NGRAPH * 32 * 4;
    int* deg     = (int*)ws;    ws += (size_t)N_NODES * 4;
    int* offs    = (int*)ws;    ws += (size_t)(N_NODES + 4) * 4;
    int* cursor  = (int*)ws;    ws += (size_t)N_NODES * 4;
    int2* edata  = (int2*)ws;   ws += (size_t)N_EDGES * 8;
    _Float16* wt_g = (_Float16*)ws; ws += (size_t)7 * 16384 * 2;
    int* cs      = (int*)ws;    ws += 64 * 4;
    int* cbase   = (int*)ws;    ws += 64 * 4;

    // --- CSR build + weight prep + casts ---
    k_zero_i<<<(N_NODES + 255) / 256, 256, 0, stream>>>(deg, N_NODES);
    k_deg<<<(N_EDGES + 255) / 256, 256, 0, stream>>>(dstp, deg);
    k_chunksum<<<NCHUNK, 256, 0, stream>>>(deg, cs);
    k_scanbase<<<1, 64, 0, stream>>>(cs, cbase, offs);
    k_scanlocal<<<NCHUNK, 1024, 0, stream>>>(deg, cbase, offs, cursor);
    k_fill<<<(N_EDGES + 255) / 256, 256, 0, stream>>>(srcp, dstp, edge_attr,
                                                      cursor, edata);
    k_wprep<<<(7 * 16384 + 255) / 256, 256, 0, stream>>>(lin_w, conv_W, wt_g);
    k_cast16<<<(N_NODES * 32 + 255) / 256, 256, 0, stream>>>(x, x16, N_NODES * 32);
    k_zero_f<<<(NGRAPH * 128 + 255) / 256, 256, 0, stream>>>(pooled, NGRAPH * 128);

    const int GGRID = (N_NODES + 63) / 64;

    // --- input linear ---
    k_gemm16<<<GGRID, 256, 0, stream>>>(x16, wt_g, lin_b, h_cur, N_NODES,
                                        nullptr, nullptr, nullptr, nullptr);

    // --- 3 residual scatter convs, 2 inner layers each ---
    for (int i = 0; i < 3; ++i) {
        const _Float16* W0 = wt_g + (size_t)(1 + i * 2 + 0) * 16384;
        const _Float16* W1 = wt_g + (size_t)(1 + i * 2 + 1) * 16384;
        const float* as0 = conv_asrc + (size_t)(i * 2 + 0) * 128;
        const float* as1 = conv_asrc + (size_t)(i * 2 + 1) * 128;
        const float* ad0 = conv_adst + (size_t)(i * 2 + 0) * 128;
        const float* ad1 = conv_adst + (size_t)(i * 2 + 1) * 128;

        k_gemm16<<<GGRID, 256, 0, stream>>>(h_cur, W0, nullptr, wx16, N_NODES,
                                            as0, ad0, a_s, a_d);
        k_attn2<<<N_NODES / 4, 256, 0, stream>>>(wx16, edata, a_s, a_d,
                                                 offs, nullptr, h_tmp);

        k_gemm16<<<GGRID, 256, 0, stream>>>(h_tmp, W1, nullptr, wx16, N_NODES,
                                            as1, ad1, a_s, a_d);
        k_attn2<<<N_NODES / 4, 256, 0, stream>>>(wx16, edata, a_s, a_d,
                                                 offs, h_cur, h_cur);
    }

    // --- pool + MLP head ---
    k_pool2<<<GGRID, 256, 0, stream>>>(h_cur, batch, pooled);
    k_mlp<128, 64><<<64, 256, 0, stream>>>(pooled, fc_w1, fc_b1, bn_g1, bn_b1, z1, 1);
    k_mlp<64, 32><<<32, 256, 0, stream>>>(z1, fc_w2, fc_b2, bn_g2, bn_b2, z2, 1);
    k_mlp<32, 10><<<10, 256, 0, stream>>>(z2, fc_w3, fc_b3, bn_g3, bn_b3, out, 0);
}